// Round 12
// baseline (391.920 us; speedup 1.0000x reference)
//
#include <hip/hip_runtime.h>
#include <hip/hip_fp16.h>
#include <cstdint>

#define IN_F 4096
#define OUT_F 4096
#define M_TOT 8192     // BATCH*SEQ = 4*2048
#define TOTAL_R 63

typedef __attribute__((ext_vector_type(8))) _Float16 f16x8;
typedef __attribute__((ext_vector_type(4))) float f32x4;
typedef __attribute__((ext_vector_type(8))) unsigned short u16x8;
typedef __attribute__((ext_vector_type(4))) unsigned short u16x4;

__device__ __forceinline__ void gload_lds16(const void* g, void* l) {
  __builtin_amdgcn_global_load_lds((const __attribute__((address_space(1))) void*)g,
                                   (__attribute__((address_space(3))) void*)l,
                                   16, 0, 0);
}

__device__ __forceinline__ int seg_of(int r) {
  // RANKS = [32,16,8,4,2,1] -> prefix 32,48,56,60,62,63
  return (r < 32) ? 0 : (r < 48) ? 1 : (r < 56) ? 2 : (r < 60) ? 3 : (r < 62) ? 4 : 5;
}

// ---------- fused prep: conv_x (f32->fp16) CONCURRENT with merge_w ----------
// r11 ran conv_x (streaming, ~35us) then merge_w (VALU/LDS, ~30us) serially
// on one stream. They are independent: stripe them into ONE grid so both are
// co-resident from dispatch start. 17408 blocks = 17 x 1024: id%17==16 ->
// merge block id/17 (1024 blocks); else conv block (16384 blocks).
// Merge per block: 64 o x 256 i; A-tile [63][256] staged in LDS once,
// read via same-address broadcast (free); scaled B^T read lane-stride-1.
__global__ __launch_bounds__(256) void prep_kernel(
    const float* __restrict__ x, const float* __restrict__ Wb,
    const float* __restrict__ A, const float* __restrict__ Bm,
    const float* __restrict__ alphas, const float* __restrict__ scalings,
    uint16_t* __restrict__ xh, uint16_t* __restrict__ wh) {
  __shared__ float sA[63 * 256];   // 63 KB   (merge branch only)
  __shared__ float sBT[63 * 64];   // 15.75 KB
  const int id = blockIdx.x;
  const int mid = id / 17, rem = id % 17;
  const int t = threadIdx.x;

  if (rem != 16) {
    // ---- conv branch: block cid of 16384, 8 floats per thread ----
    const int cid = mid * 16 + rem;
    size_t i = (size_t)cid * 256 + t;
    const float4* xv = (const float4*)x;
    float4 v0 = xv[2 * i];
    float4 v1 = xv[2 * i + 1];
    float v[8] = {v0.x, v0.y, v0.z, v0.w, v1.x, v1.y, v1.z, v1.w};
    u16x8 h;
#pragma unroll
    for (int k = 0; k < 8; ++k) h[k] = __half_as_ushort(__float2half_rn(v[k]));
    *(u16x8*)(xh + 8 * i) = h;
    return;
  }

  // ---- merge branch: block mid of 1024 ----
  const int bo = mid >> 4, bi = mid & 15;
  const int o0 = bo * 64, i0 = bi * 256;
  const int wv = t >> 6, ln = t & 63;

#pragma unroll
  for (int k = 0; k < 16; ++k) {
    int r = k * 4 + wv;
    if (r < 63) {
      f32x4 v = *(const f32x4*)(A + (size_t)r * IN_F + i0 + ln * 4);
      *(f32x4*)(sA + r * 256 + ln * 4) = v;
    }
  }
  {
    const int oo = ln;
    const int rbase = wv * 16;
#pragma unroll
    for (int rr = 0; rr < 16; ++rr) {
      int r = rbase + rr;
      if (r < 63) {
        int s = seg_of(r);
        sBT[r * 64 + oo] = Bm[(size_t)(o0 + oo) * TOTAL_R + r] * alphas[s] * scalings[s];
      }
    }
  }
  __syncthreads();

  const int oo = t & 63, iq = t >> 6;   // thread: one o, 64 i's
  const size_t obase = (size_t)(o0 + oo) * IN_F + i0 + iq * 64;
  f32x4 acc4[16];
#pragma unroll
  for (int v = 0; v < 16; ++v) acc4[v] = *(const f32x4*)(Wb + obase + v * 4);
#pragma unroll 9
  for (int r = 0; r < 63; ++r) {
    const float coeff = sBT[r * 64 + oo];           // lane-stride-1: free
    const f32x4* ar = (const f32x4*)(sA + r * 256 + iq * 64);  // broadcast: free
#pragma unroll
    for (int v = 0; v < 16; ++v) acc4[v] += coeff * ar[v];
  }
#pragma unroll
  for (int v = 0; v < 16; ++v) {
    u16x4 h;
#pragma unroll
    for (int k = 0; k < 4; ++k) h[k] = __half_as_ushort(__float2half_rn(acc4[v][k]));
    *(u16x4*)(wh + obase + v * 4) = h;
  }
}

// ---------- fp16 GEMM, m201-style 8-phase/2-tile schedule (r11, FROZEN) ----------
// out = xh @ wh^T + bias. 256x256 tile, BK=64, 512 threads (8 waves 2Mx4N),
// wave tile 128x64, mfma 16x16x32_f16. LDS 128KB: [dbuf][X/W][khalf] x
// (256 rows x 32 halfs) in the r7-proven zero-conflict pack (2 rows/128B
// line, slot swizzle phys = slog^(line&7), pre-swizzled gload source).
// 4 phases per K-tile (ih,ks), 16 MFMA each; one half-tile staged per phase
// into dbuf^1; counted vmcnt(4) twice per K-tile, never 0 until last tile.
// Measured r11: 250us, MfmaUtil 51, conflicts 0.
__global__ __launch_bounds__(512, 2) void gemm_mrlora(
    const uint16_t* __restrict__ xh, const uint16_t* __restrict__ wh,
    const float* __restrict__ bias, float* __restrict__ out) {
  __shared__ uint16_t lds[2][2][2][8192];   // 128 KB
  const int t = threadIdx.x;
  const int l = t & 63;
  const int w = t >> 6;                  // 0..7
  const int wm = w >> 2, wn = w & 3;     // wave tile: rows wm*128, cols wn*64
  const int lr = l & 15, lg = l >> 4;

  // raster: XCD chunk (64 blocks) covers 4 bm x 16 bn, bm-minor
  const int xcd = blockIdx.x & 7;
  const int kk = blockIdx.x >> 3;        // 0..63
  const int bm = xcd * 4 + (kk & 3);     // 0..31
  const int bn = kk >> 2;                // 0..15
  const size_t brow = (size_t)bm * 256;
  const size_t bcol = (size_t)bn * 256;

  // staging source map (r7-proven): chunk D = g*512 + t -> line g*64+(t>>3),
  // phys slot t&7; slog = (t&7)^((t>>3)&7); row = g*128+(t>>3)*2+(slog>>2);
  // col-in-khalf = (slog&3)*8.
  const int sp = (t & 7) ^ ((t >> 3) & 7);
  const int grow = (t >> 3) * 2 + (sp >> 2);
  const int gcol = (sp & 3) * 8;
  const uint16_t* pX = xh + (brow + grow) * (size_t)IN_F + gcol;
  const uint16_t* pW = wh + (bcol + grow) * (size_t)IN_F + gcol;
  const int t8 = t * 8;

  // fragment read offsets (halfs): row -> line=row>>1, slog=(row&1)*4+lg,
  // phys = slog ^ (line&7)  [zero-conflict, r7-measured]
  int aoff[2][4], boff[4];
#pragma unroll
  for (int ih = 0; ih < 2; ++ih)
#pragma unroll
    for (int i2 = 0; i2 < 4; ++i2) {
      int row = wm * 128 + ih * 64 + i2 * 16 + lr;
      aoff[ih][i2] = (row >> 1) * 64 + (((((row & 1) << 2) | lg) ^ ((row >> 1) & 7)) << 3);
    }
#pragma unroll
  for (int j = 0; j < 4; ++j) {
    int row = wn * 64 + j * 16 + lr;
    boff[j] = (row >> 1) * 64 + (((((row & 1) << 2) | lg) ^ ((row >> 1) & 7)) << 3);
  }

  f32x4 acc[8][4] = {};
  f16x8 afr[4], bfr[4];

#define STG(NB, MAT, KS, KT)                                                   \
  do {                                                                         \
    const uint16_t* _s = ((MAT) ? pW : pX) + (KT) * 64 + (KS) * 32;            \
    gload_lds16(_s, &lds[NB][MAT][KS][t8]);                                    \
    gload_lds16(_s + 128 * (size_t)IN_F, &lds[NB][MAT][KS][t8 + 4096]);        \
  } while (0)

#define RDA(BUF, IH, KS)                                                       \
  _Pragma("unroll") for (int _i = 0; _i < 4; ++_i)                             \
      afr[_i] = *(const f16x8*)&lds[BUF][0][KS][aoff[IH][_i]];

#define RDB(BUF, KS)                                                           \
  _Pragma("unroll") for (int _j = 0; _j < 4; ++_j)                             \
      bfr[_j] = *(const f16x8*)&lds[BUF][1][KS][boff[_j]];

#define MM16(IH, KS)                                                           \
  do {                                                                         \
    __builtin_amdgcn_s_setprio(1);                                             \
    _Pragma("unroll") for (int _i = 0; _i < 4; ++_i)                           \
        _Pragma("unroll") for (int _j = 0; _j < 4; ++_j)                       \
            acc[(IH) * 4 + _i][_j] = __builtin_amdgcn_mfma_f32_16x16x32_f16(   \
                afr[_i], bfr[_j], acc[(IH) * 4 + _i][_j], 0, 0, 0);            \
    __builtin_amdgcn_s_setprio(0);                                             \
  } while (0)

#define BAR __builtin_amdgcn_s_barrier()

#define KTILE(BUF, KT, S2W, S4W, DOSTG)                                        \
  do {                                                                         \
    /* phase 1: ih=0, ks=0 */                                                  \
    RDA(BUF, 0, 0); RDB(BUF, 0);                                               \
    if (DOSTG) STG(1 - (BUF), 0, 0, (KT) + 1);                                 \
    BAR;                                                                       \
    MM16(0, 0);                                                                \
    BAR;                                                                       \
    /* phase 2: ih=1, ks=0 (B held) */                                         \
    RDA(BUF, 1, 0);                                                            \
    if (DOSTG) STG(1 - (BUF), 1, 0, (KT) + 1);                                 \
    BAR;                                                                       \
    MM16(1, 0);                                                                \
    asm volatile("s_waitcnt " S2W ::: "memory");  /* ks1 halves of KT landed */\
    BAR;                                                                       \
    /* phase 3: ih=0, ks=1 */                                                  \
    RDA(BUF, 0, 1); RDB(BUF, 1);                                               \
    if (DOSTG) STG(1 - (BUF), 0, 1, (KT) + 1);                                 \
    BAR;                                                                       \
    MM16(0, 1);                                                                \
    BAR;                                                                       \
    /* phase 4: ih=1, ks=1 (B held) */                                         \
    RDA(BUF, 1, 1);                                                            \
    if (DOSTG) STG(1 - (BUF), 1, 1, (KT) + 1);                                 \
    BAR;                                                                       \
    MM16(1, 1);                                                                \
    asm volatile("s_waitcnt " S4W ::: "memory");  /* ks0 of KT+1 landed */     \
    BAR;                                                                       \
  } while (0)

  // prologue: tile 0 fully issued (8 loads), release its ks0 halves
  STG(0, 0, 0, 0); STG(0, 1, 0, 0); STG(0, 0, 1, 0); STG(0, 1, 1, 0);
  asm volatile("s_waitcnt vmcnt(4)" ::: "memory");
  BAR;

#pragma unroll 1
  for (int tt = 0; tt < 31; ++tt) {
    KTILE(0, 2 * tt,     "vmcnt(4)", "vmcnt(4)", 1);
    KTILE(1, 2 * tt + 1, "vmcnt(4)", "vmcnt(4)", 1);
  }
  KTILE(0, 62, "vmcnt(4)", "vmcnt(4)", 1);
  KTILE(1, 63, "vmcnt(0)", "vmcnt(0)", 0);

#undef KTILE
#undef BAR
#undef MM16
#undef RDB
#undef RDA
#undef STG

  // epilogue: D layout col = lane&15, row = (lane>>4)*4 + reg
#pragma unroll
  for (int j = 0; j < 4; ++j) {
    const size_t col = bcol + wn * 64 + j * 16 + lr;
    const float bs = bias[col];
#pragma unroll
    for (int i = 0; i < 8; ++i) {
      const size_t row0 = brow + wm * 128 + i * 16 + lg * 4;
#pragma unroll
      for (int r = 0; r < 4; ++r)
        out[(row0 + r) * OUT_F + col] = acc[i][j][r] + bs;
    }
  }
}

// ================= fallback path (small workspace): fp32 =================

__global__ __launch_bounds__(256) void fb_z_kernel(const float* __restrict__ x,
                                                   const float* __restrict__ A,
                                                   const float* __restrict__ alphas,
                                                   const float* __restrict__ scalings,
                                                   float* __restrict__ z) {
  __shared__ float sx[IN_F];
  __shared__ float red[256];
  const int m = blockIdx.x, t = threadIdx.x;
  for (int i = t; i < IN_F / 4; i += 256)
    ((float4*)sx)[i] = ((const float4*)(x + (size_t)m * IN_F))[i];
  __syncthreads();
  const int r = t >> 2, q = t & 3;
  float part = 0.f;
  if (r < TOTAL_R) {
    const float4* Ar = (const float4*)(A + (size_t)r * IN_F + q * 1024);
    const float4* xs = (const float4*)(sx + q * 1024);
    for (int k = 0; k < 256; ++k) {
      float4 av = Ar[k], xv = xs[k];
      part += av.x * xv.x + av.y * xv.y + av.z * xv.z + av.w * xv.w;
    }
  }
  red[t] = part;
  __syncthreads();
  if (q == 0 && r < TOTAL_R) {
    int s = seg_of(r);
    z[(size_t)m * TOTAL_R + r] =
        alphas[s] * scalings[s] * (red[t] + red[t + 1] + red[t + 2] + red[t + 3]);
  }
}

__global__ __launch_bounds__(256) void fb_gemm_fp32(const float* __restrict__ x,
                                                    const float* __restrict__ Wb,
                                                    const float* __restrict__ bb,
                                                    const float* __restrict__ Bm,
                                                    const float* __restrict__ z,
                                                    float* __restrict__ out) {
  __shared__ float sx[64][33];
  __shared__ float sw[64][33];
  const int t = threadIdx.x;
  const int tr = t >> 4, tc = t & 15;
  const int bm = blockIdx.x / (OUT_F / 64);
  const int bn = blockIdx.x % (OUT_F / 64);
  const size_t brow = (size_t)bm * 64, bcol = (size_t)bn * 64;
  const int r = t >> 2, c0 = (t & 3) * 8;
  float acc[4][4] = {};
  for (int k0 = 0; k0 < IN_F; k0 += 32) {
    float4 a0 = *(const float4*)(x + (brow + r) * IN_F + k0 + c0);
    float4 a1 = *(const float4*)(x + (brow + r) * IN_F + k0 + c0 + 4);
    float4 w0 = *(const float4*)(Wb + (bcol + r) * IN_F + k0 + c0);
    float4 w1 = *(const float4*)(Wb + (bcol + r) * IN_F + k0 + c0 + 4);
    __syncthreads();
    sx[r][c0 + 0] = a0.x; sx[r][c0 + 1] = a0.y; sx[r][c0 + 2] = a0.z; sx[r][c0 + 3] = a0.w;
    sx[r][c0 + 4] = a1.x; sx[r][c0 + 5] = a1.y; sx[r][c0 + 6] = a1.z; sx[r][c0 + 7] = a1.w;
    sw[r][c0 + 0] = w0.x; sw[r][c0 + 1] = w0.y; sw[r][c0 + 2] = w0.z; sw[r][c0 + 3] = w0.w;
    sw[r][c0 + 4] = w1.x; sw[r][c0 + 5] = w1.y; sw[r][c0 + 6] = w1.z; sw[r][c0 + 7] = w1.w;
    __syncthreads();
#pragma unroll
    for (int k = 0; k < 32; ++k) {
      float xa[4], wv[4];
#pragma unroll
      for (int i = 0; i < 4; ++i) xa[i] = sx[tr + 16 * i][k];
#pragma unroll
      for (int j = 0; j < 4; ++j) wv[j] = sw[tc + 16 * j][k];
#pragma unroll
      for (int i = 0; i < 4; ++i)
#pragma unroll
        for (int j = 0; j < 4; ++j) acc[i][j] += xa[i] * wv[j];
    }
  }
#pragma unroll 1
  for (int rr = 0; rr < TOTAL_R; ++rr) {
    float zr[4], br[4];
#pragma unroll
    for (int i = 0; i < 4; ++i) zr[i] = z[(brow + tr + 16 * i) * TOTAL_R + rr];
#pragma unroll
    for (int j = 0; j < 4; ++j) br[j] = Bm[(bcol + tc + 16 * j) * TOTAL_R + rr];
#pragma unroll
    for (int i = 0; i < 4; ++i)
#pragma unroll
      for (int j = 0; j < 4; ++j) acc[i][j] += zr[i] * br[j];
  }
#pragma unroll
  for (int i = 0; i < 4; ++i)
#pragma unroll
    for (int j = 0; j < 4; ++j) {
      size_t row = brow + tr + 16 * i, col = bcol + tc + 16 * j;
      out[row * OUT_F + col] = acc[i][j] + bb[col];
    }
}

extern "C" void kernel_launch(void* const* d_in, const int* in_sizes, int n_in,
                              void* d_out, int out_size, void* d_ws, size_t ws_size,
                              hipStream_t stream) {
  const float* x  = (const float*)d_in[0];
  const float* Wb = (const float*)d_in[1];
  const float* bb = (const float*)d_in[2];
  const float* A  = (const float*)d_in[3];
  const float* Bm = (const float*)d_in[4];
  const float* al = (const float*)d_in[5];
  const float* sc = (const float*)d_in[6];
  float* out = (float*)d_out;

  const size_t MB = (size_t)1 << 20;
  if (ws_size >= 96 * MB) {
    char* ws = (char*)d_ws;
    uint16_t* xh = (uint16_t*)(ws);             // 64 MB fp16
    uint16_t* wh = (uint16_t*)(ws + 64 * MB);   // 32 MB fp16
    // fused prep: 16384 conv blocks + 1024 merge blocks, striped 16:1
    prep_kernel<<<17408, 256, 0, stream>>>(x, Wb, A, Bm, al, sc, xh, wh);
    gemm_mrlora<<<(M_TOT / 256) * (OUT_F / 256), 512, 0, stream>>>(xh, wh, bb, out);
  } else {
    float* z = (float*)d_ws;  // needs 8192*63*4 ~= 2 MB
    fb_z_kernel<<<M_TOT, 256, 0, stream>>>(x, A, al, sc, z);
    fb_gemm_fp32<<<(M_TOT / 64) * (OUT_F / 64), 256, 0, stream>>>(x, Wb, bb, Bm, z, out);
  }
}

// Round 13
// 335.290 us; speedup vs baseline: 1.1689x; 1.1689x over previous
//
#include <hip/hip_runtime.h>
#include <hip/hip_fp16.h>
#include <cstdint>

#define IN_F 4096
#define OUT_F 4096
#define M_TOT 8192     // BATCH*SEQ = 4*2048
#define TOTAL_R 63

typedef __attribute__((ext_vector_type(8))) _Float16 f16x8;
typedef __attribute__((ext_vector_type(4))) float f32x4;
typedef __attribute__((ext_vector_type(8))) unsigned short u16x8;
typedef __attribute__((ext_vector_type(4))) unsigned short u16x4;

__device__ __forceinline__ void gload_lds16(const void* g, void* l) {
  __builtin_amdgcn_global_load_lds((const __attribute__((address_space(1))) void*)g,
                                   (__attribute__((address_space(3))) void*)l,
                                   16, 0, 0);
}

__device__ __forceinline__ int seg_of(int r) {
  // RANKS = [32,16,8,4,2,1] -> prefix 32,48,56,60,62,63
  return (r < 32) ? 0 : (r < 48) ? 1 : (r < 56) ? 2 : (r < 60) ? 3 : (r < 62) ? 4 : 5;
}

// ---------- fused prep v2: conv_x CONCURRENT with merge_w, small-LDS ----------
// r12 regression cause: merge's 79KB static LDS was charged to ALL blocks ->
// conv occupancy 2 blocks/CU -> block-turnover-limited. Fix: merge branch
// uses only 31.75KB LDS (A-tile [63][128] + 256B coeff table; B coeffs read
// per-thread from global, L1/L2-hot) -> 5 blocks/CU for every block.
// 18432 blocks = 9 x 2048: id%9==8 -> merge block id/9 (2048 of 64o x 128i);
// else conv block (16384).
__global__ __launch_bounds__(256) void prep_kernel(
    const float* __restrict__ x, const float* __restrict__ Wb,
    const float* __restrict__ A, const float* __restrict__ Bm,
    const float* __restrict__ alphas, const float* __restrict__ scalings,
    uint16_t* __restrict__ xh, uint16_t* __restrict__ wh) {
  __shared__ float sA[63 * 128];   // 31.5 KB
  __shared__ float sCS[64];        // alpha*scaling per r (63 used)
  const int id = blockIdx.x;
  const int q9 = id / 9, rem = id % 9;
  const int t = threadIdx.x;

  if (rem != 8) {
    // ---- conv branch: block cid of 16384, 8 floats per thread ----
    const int cid = q9 * 8 + rem;
    size_t i = (size_t)cid * 256 + t;
    const float4* xv = (const float4*)x;
    float4 v0 = xv[2 * i];
    float4 v1 = xv[2 * i + 1];
    float v[8] = {v0.x, v0.y, v0.z, v0.w, v1.x, v1.y, v1.z, v1.w};
    u16x8 h;
#pragma unroll
    for (int k = 0; k < 8; ++k) h[k] = __half_as_ushort(__float2half_rn(v[k]));
    *(u16x8*)(xh + 8 * i) = h;
    return;
  }

  // ---- merge branch: block mid of 2048 (64 o x 128 i) ----
  const int mid = q9;
  const int o0 = (mid >> 5) * 64, i0 = (mid & 31) * 128;

  if (t < 64) {
    int r = t;
    sCS[t] = (r < TOTAL_R) ? alphas[seg_of(r)] * scalings[seg_of(r)] : 0.f;
  }
  // stage A: 63 rows x 32 f32x4 chunks = 2016 chunks
#pragma unroll
  for (int k = 0; k < 8; ++k) {
    int idx = k * 256 + t;
    if (idx < 63 * 32) {
      int r = idx >> 5, c = idx & 31;
      *(f32x4*)(sA + r * 128 + c * 4) =
          *(const f32x4*)(A + (size_t)r * IN_F + i0 + c * 4);
    }
  }
  __syncthreads();

  const int oo = t & 63, iq = t >> 6;   // thread: one o, 32 i's
  const size_t ob = (size_t)(o0 + oo);
  const size_t obase = ob * IN_F + i0 + iq * 32;
  const float* bmrow = Bm + ob * TOTAL_R;
  f32x4 acc4[8];
#pragma unroll
  for (int v = 0; v < 8; ++v) acc4[v] = *(const f32x4*)(Wb + obase + v * 4);
#pragma unroll 9
  for (int r = 0; r < TOTAL_R; ++r) {
    const float coeff = bmrow[r] * sCS[r];             // 252B row, L1-hot
    const f32x4* ar = (const f32x4*)(sA + r * 128 + iq * 32);  // wave-broadcast
#pragma unroll
    for (int v = 0; v < 8; ++v) acc4[v] += coeff * ar[v];
  }
#pragma unroll
  for (int v = 0; v < 8; ++v) {
    u16x4 h;
#pragma unroll
    for (int k = 0; k < 4; ++k) h[k] = __half_as_ushort(__float2half_rn(acc4[v][k]));
    *(u16x4*)(wh + obase + v * 4) = h;
  }
}

// ---------- fp16 GEMM, m201-style 8-phase/2-tile schedule (r11, FROZEN) ----------
// out = xh @ wh^T + bias. 256x256 tile, BK=64, 512 threads (8 waves 2Mx4N),
// wave tile 128x64, mfma 16x16x32_f16. LDS 128KB: [dbuf][X/W][khalf] x
// (256 rows x 32 halfs) in the r7-proven zero-conflict pack (2 rows/128B
// line, slot swizzle phys = slog^(line&7), pre-swizzled gload source).
// 4 phases per K-tile (ih,ks), 16 MFMA each; one half-tile staged per phase
// into dbuf^1; counted vmcnt(4) twice per K-tile, never 0 until last tile.
// Measured r11/r12: 250-255us, MfmaUtil 51, conflicts 0.
__global__ __launch_bounds__(512, 2) void gemm_mrlora(
    const uint16_t* __restrict__ xh, const uint16_t* __restrict__ wh,
    const float* __restrict__ bias, float* __restrict__ out) {
  __shared__ uint16_t lds[2][2][2][8192];   // 128 KB
  const int t = threadIdx.x;
  const int l = t & 63;
  const int w = t >> 6;                  // 0..7
  const int wm = w >> 2, wn = w & 3;     // wave tile: rows wm*128, cols wn*64
  const int lr = l & 15, lg = l >> 4;

  // raster: XCD chunk (64 blocks) covers 4 bm x 16 bn, bm-minor
  const int xcd = blockIdx.x & 7;
  const int kk = blockIdx.x >> 3;        // 0..63
  const int bm = xcd * 4 + (kk & 3);     // 0..31
  const int bn = kk >> 2;                // 0..15
  const size_t brow = (size_t)bm * 256;
  const size_t bcol = (size_t)bn * 256;

  // staging source map (r7-proven): chunk D = g*512 + t -> line g*64+(t>>3),
  // phys slot t&7; slog = (t&7)^((t>>3)&7); row = g*128+(t>>3)*2+(slog>>2);
  // col-in-khalf = (slog&3)*8.
  const int sp = (t & 7) ^ ((t >> 3) & 7);
  const int grow = (t >> 3) * 2 + (sp >> 2);
  const int gcol = (sp & 3) * 8;
  const uint16_t* pX = xh + (brow + grow) * (size_t)IN_F + gcol;
  const uint16_t* pW = wh + (bcol + grow) * (size_t)IN_F + gcol;
  const int t8 = t * 8;

  // fragment read offsets (halfs): row -> line=row>>1, slog=(row&1)*4+lg,
  // phys = slog ^ (line&7)  [zero-conflict, r7-measured]
  int aoff[2][4], boff[4];
#pragma unroll
  for (int ih = 0; ih < 2; ++ih)
#pragma unroll
    for (int i2 = 0; i2 < 4; ++i2) {
      int row = wm * 128 + ih * 64 + i2 * 16 + lr;
      aoff[ih][i2] = (row >> 1) * 64 + (((((row & 1) << 2) | lg) ^ ((row >> 1) & 7)) << 3);
    }
#pragma unroll
  for (int j = 0; j < 4; ++j) {
    int row = wn * 64 + j * 16 + lr;
    boff[j] = (row >> 1) * 64 + (((((row & 1) << 2) | lg) ^ ((row >> 1) & 7)) << 3);
  }

  f32x4 acc[8][4] = {};
  f16x8 afr[4], bfr[4];

#define STG(NB, MAT, KS, KT)                                                   \
  do {                                                                         \
    const uint16_t* _s = ((MAT) ? pW : pX) + (KT) * 64 + (KS) * 32;            \
    gload_lds16(_s, &lds[NB][MAT][KS][t8]);                                    \
    gload_lds16(_s + 128 * (size_t)IN_F, &lds[NB][MAT][KS][t8 + 4096]);        \
  } while (0)

#define RDA(BUF, IH, KS)                                                       \
  _Pragma("unroll") for (int _i = 0; _i < 4; ++_i)                             \
      afr[_i] = *(const f16x8*)&lds[BUF][0][KS][aoff[IH][_i]];

#define RDB(BUF, KS)                                                           \
  _Pragma("unroll") for (int _j = 0; _j < 4; ++_j)                             \
      bfr[_j] = *(const f16x8*)&lds[BUF][1][KS][boff[_j]];

#define MM16(IH, KS)                                                           \
  do {                                                                         \
    __builtin_amdgcn_s_setprio(1);                                             \
    _Pragma("unroll") for (int _i = 0; _i < 4; ++_i)                           \
        _Pragma("unroll") for (int _j = 0; _j < 4; ++_j)                       \
            acc[(IH) * 4 + _i][_j] = __builtin_amdgcn_mfma_f32_16x16x32_f16(   \
                afr[_i], bfr[_j], acc[(IH) * 4 + _i][_j], 0, 0, 0);            \
    __builtin_amdgcn_s_setprio(0);                                             \
  } while (0)

#define BAR __builtin_amdgcn_s_barrier()

#define KTILE(BUF, KT, S2W, S4W, DOSTG)                                        \
  do {                                                                         \
    /* phase 1: ih=0, ks=0 */                                                  \
    RDA(BUF, 0, 0); RDB(BUF, 0);                                               \
    if (DOSTG) STG(1 - (BUF), 0, 0, (KT) + 1);                                 \
    BAR;                                                                       \
    MM16(0, 0);                                                                \
    BAR;                                                                       \
    /* phase 2: ih=1, ks=0 (B held) */                                         \
    RDA(BUF, 1, 0);                                                            \
    if (DOSTG) STG(1 - (BUF), 1, 0, (KT) + 1);                                 \
    BAR;                                                                       \
    MM16(1, 0);                                                                \
    asm volatile("s_waitcnt " S2W ::: "memory");  /* ks1 halves of KT landed */\
    BAR;                                                                       \
    /* phase 3: ih=0, ks=1 */                                                  \
    RDA(BUF, 0, 1); RDB(BUF, 1);                                               \
    if (DOSTG) STG(1 - (BUF), 0, 1, (KT) + 1);                                 \
    BAR;                                                                       \
    MM16(0, 1);                                                                \
    BAR;                                                                       \
    /* phase 4: ih=1, ks=1 (B held) */                                         \
    RDA(BUF, 1, 1);                                                            \
    if (DOSTG) STG(1 - (BUF), 1, 1, (KT) + 1);                                 \
    BAR;                                                                       \
    MM16(1, 1);                                                                \
    asm volatile("s_waitcnt " S4W ::: "memory");  /* ks0 of KT+1 landed */     \
    BAR;                                                                       \
  } while (0)

  // prologue: tile 0 fully issued (8 loads), release its ks0 halves
  STG(0, 0, 0, 0); STG(0, 1, 0, 0); STG(0, 0, 1, 0); STG(0, 1, 1, 0);
  asm volatile("s_waitcnt vmcnt(4)" ::: "memory");
  BAR;

#pragma unroll 1
  for (int tt = 0; tt < 31; ++tt) {
    KTILE(0, 2 * tt,     "vmcnt(4)", "vmcnt(4)", 1);
    KTILE(1, 2 * tt + 1, "vmcnt(4)", "vmcnt(4)", 1);
  }
  KTILE(0, 62, "vmcnt(4)", "vmcnt(4)", 1);
  KTILE(1, 63, "vmcnt(0)", "vmcnt(0)", 0);

#undef KTILE
#undef BAR
#undef MM16
#undef RDB
#undef RDA
#undef STG

  // epilogue: D layout col = lane&15, row = (lane>>4)*4 + reg
#pragma unroll
  for (int j = 0; j < 4; ++j) {
    const size_t col = bcol + wn * 64 + j * 16 + lr;
    const float bs = bias[col];
#pragma unroll
    for (int i = 0; i < 8; ++i) {
      const size_t row0 = brow + wm * 128 + i * 16 + lg * 4;
#pragma unroll
      for (int r = 0; r < 4; ++r)
        out[(row0 + r) * OUT_F + col] = acc[i][j][r] + bs;
    }
  }
}

// ================= fallback path (small workspace): fp32 =================

__global__ __launch_bounds__(256) void fb_z_kernel(const float* __restrict__ x,
                                                   const float* __restrict__ A,
                                                   const float* __restrict__ alphas,
                                                   const float* __restrict__ scalings,
                                                   float* __restrict__ z) {
  __shared__ float sx[IN_F];
  __shared__ float red[256];
  const int m = blockIdx.x, t = threadIdx.x;
  for (int i = t; i < IN_F / 4; i += 256)
    ((float4*)sx)[i] = ((const float4*)(x + (size_t)m * IN_F))[i];
  __syncthreads();
  const int r = t >> 2, q = t & 3;
  float part = 0.f;
  if (r < TOTAL_R) {
    const float4* Ar = (const float4*)(A + (size_t)r * IN_F + q * 1024);
    const float4* xs = (const float4*)(sx + q * 1024);
    for (int k = 0; k < 256; ++k) {
      float4 av = Ar[k], xv = xs[k];
      part += av.x * xv.x + av.y * xv.y + av.z * xv.z + av.w * xv.w;
    }
  }
  red[t] = part;
  __syncthreads();
  if (q == 0 && r < TOTAL_R) {
    int s = seg_of(r);
    z[(size_t)m * TOTAL_R + r] =
        alphas[s] * scalings[s] * (red[t] + red[t + 1] + red[t + 2] + red[t + 3]);
  }
}

__global__ __launch_bounds__(256) void fb_gemm_fp32(const float* __restrict__ x,
                                                    const float* __restrict__ Wb,
                                                    const float* __restrict__ bb,
                                                    const float* __restrict__ Bm,
                                                    const float* __restrict__ z,
                                                    float* __restrict__ out) {
  __shared__ float sx[64][33];
  __shared__ float sw[64][33];
  const int t = threadIdx.x;
  const int tr = t >> 4, tc = t & 15;
  const int bm = blockIdx.x / (OUT_F / 64);
  const int bn = blockIdx.x % (OUT_F / 64);
  const size_t brow = (size_t)bm * 64, bcol = (size_t)bn * 64;
  const int r = t >> 2, c0 = (t & 3) * 8;
  float acc[4][4] = {};
  for (int k0 = 0; k0 < IN_F; k0 += 32) {
    float4 a0 = *(const float4*)(x + (brow + r) * IN_F + k0 + c0);
    float4 a1 = *(const float4*)(x + (brow + r) * IN_F + k0 + c0 + 4);
    float4 w0 = *(const float4*)(Wb + (bcol + r) * IN_F + k0 + c0);
    float4 w1 = *(const float4*)(Wb + (bcol + r) * IN_F + k0 + c0 + 4);
    __syncthreads();
    sx[r][c0 + 0] = a0.x; sx[r][c0 + 1] = a0.y; sx[r][c0 + 2] = a0.z; sx[r][c0 + 3] = a0.w;
    sx[r][c0 + 4] = a1.x; sx[r][c0 + 5] = a1.y; sx[r][c0 + 6] = a1.z; sx[r][c0 + 7] = a1.w;
    sw[r][c0 + 0] = w0.x; sw[r][c0 + 1] = w0.y; sw[r][c0 + 2] = w0.z; sw[r][c0 + 3] = w0.w;
    sw[r][c0 + 4] = w1.x; sw[r][c0 + 5] = w1.y; sw[r][c0 + 6] = w1.z; sw[r][c0 + 7] = w1.w;
    __syncthreads();
#pragma unroll
    for (int k = 0; k < 32; ++k) {
      float xa[4], wv[4];
#pragma unroll
      for (int i = 0; i < 4; ++i) xa[i] = sx[tr + 16 * i][k];
#pragma unroll
      for (int j = 0; j < 4; ++j) wv[j] = sw[tc + 16 * j][k];
#pragma unroll
      for (int i = 0; i < 4; ++i)
#pragma unroll
        for (int j = 0; j < 4; ++j) acc[i][j] += xa[i] * wv[j];
    }
  }
#pragma unroll 1
  for (int rr = 0; rr < TOTAL_R; ++rr) {
    float zr[4], br[4];
#pragma unroll
    for (int i = 0; i < 4; ++i) zr[i] = z[(brow + tr + 16 * i) * TOTAL_R + rr];
#pragma unroll
    for (int j = 0; j < 4; ++j) br[j] = Bm[(bcol + tc + 16 * j) * TOTAL_R + rr];
#pragma unroll
    for (int i = 0; i < 4; ++i)
#pragma unroll
      for (int j = 0; j < 4; ++j) acc[i][j] += zr[i] * br[j];
  }
#pragma unroll
  for (int i = 0; i < 4; ++i)
#pragma unroll
    for (int j = 0; j < 4; ++j) {
      size_t row = brow + tr + 16 * i, col = bcol + tc + 16 * j;
      out[row * OUT_F + col] = acc[i][j] + bb[col];
    }
}

extern "C" void kernel_launch(void* const* d_in, const int* in_sizes, int n_in,
                              void* d_out, int out_size, void* d_ws, size_t ws_size,
                              hipStream_t stream) {
  const float* x  = (const float*)d_in[0];
  const float* Wb = (const float*)d_in[1];
  const float* bb = (const float*)d_in[2];
  const float* A  = (const float*)d_in[3];
  const float* Bm = (const float*)d_in[4];
  const float* al = (const float*)d_in[5];
  const float* sc = (const float*)d_in[6];
  float* out = (float*)d_out;

  const size_t MB = (size_t)1 << 20;
  if (ws_size >= 96 * MB) {
    char* ws = (char*)d_ws;
    uint16_t* xh = (uint16_t*)(ws);             // 64 MB fp16
    uint16_t* wh = (uint16_t*)(ws + 64 * MB);   // 32 MB fp16
    // fused prep v2: 16384 conv blocks + 2048 merge blocks, striped 8:1
    prep_kernel<<<18432, 256, 0, stream>>>(x, Wb, A, Bm, al, sc, xh, wh);
    gemm_mrlora<<<(M_TOT / 256) * (OUT_F / 256), 512, 0, stream>>>(xh, wh, bb, out);
  } else {
    float* z = (float*)d_ws;  // needs 8192*63*4 ~= 2 MB
    fb_z_kernel<<<M_TOT, 256, 0, stream>>>(x, A, al, sc, z);
    fb_gemm_fp32<<<(M_TOT / 64) * (OUT_F / 64), 256, 0, stream>>>(x, Wb, bb, Bm, z, out);
  }
}